// Round 1
// 921.896 us; speedup vs baseline: 1.0045x; 1.0045x over previous
//
#include <hip/hip_runtime.h>
#include <cstdint>
#include <cstddef>

// Problem constants (B=4, S=2048 -> T=8192 tokens)
#define T_TOK 8192
#define H_DIM 1024
#define F_DIM 3584
#define E_NUM 8
#define MAX_ROWS 17408   // 2T assignments + per-expert pad to 128
#define MAX_TILES 136    // ceil-sum of per-expert tiles, worst case

typedef __bf16 bf16_t;
typedef bf16_t bf16x8 __attribute__((ext_vector_type(8)));
typedef bf16_t bf16x4 __attribute__((ext_vector_type(4)));
typedef float floatx4 __attribute__((ext_vector_type(4)));

typedef const __attribute__((address_space(1))) void* gas_ptr;
typedef __attribute__((address_space(3))) void* las_ptr;

// async global->LDS, 16B per lane. LDS dest is wave-uniform base + lane*16;
// global address is per-lane (gather OK).
__device__ __forceinline__ void async_copy16(const void* g, void* l) {
    __builtin_amdgcn_global_load_lds((gas_ptr)g, (las_ptr)l, 16, 0, 0);
}

#define WAIT_VM0() asm volatile("s_waitcnt vmcnt(0)" ::: "memory")
#define BAR() __builtin_amdgcn_s_barrier()

// ---------------- elementwise fp32 -> bf16 cast (4 elems/thread) ----------------
__global__ void cast_f32_to_bf16(const float* __restrict__ in, bf16_t* __restrict__ out, int n4) {
    int i = blockIdx.x * blockDim.x + threadIdx.x;
    if (i < n4) {
        const float4 v = ((const float4*)in)[i];
        bf16x4 o;
        o[0] = (bf16_t)v.x; o[1] = (bf16_t)v.y; o[2] = (bf16_t)v.z; o[3] = (bf16_t)v.w;
        ((bf16x4*)out)[i] = o;
    }
}

// ---------------- w2 [E,F,H] fp32 -> w2t [E,H,F] bf16 (tiled transpose) ----------------
__global__ void transpose_cast_w2(const float* __restrict__ W2, bf16_t* __restrict__ W2T) {
    __shared__ bf16_t tile[32][34];
    const int e = blockIdx.z;
    const int f0 = blockIdx.x * 32;
    const int h0 = blockIdx.y * 32;
    const float* src = W2 + (size_t)e * F_DIM * H_DIM;
    bf16_t* dst = W2T + (size_t)e * H_DIM * F_DIM;
    const int tx = threadIdx.x;  // 0..31
    const int ty = threadIdx.y;  // 0..7
#pragma unroll
    for (int r = 0; r < 32; r += 8)
        tile[ty + r][tx] = (bf16_t)src[(size_t)(f0 + ty + r) * H_DIM + (h0 + tx)];
    __syncthreads();
#pragma unroll
    for (int r = 0; r < 32; r += 8)
        dst[(size_t)(h0 + ty + r) * F_DIM + (f0 + tx)] = tile[tx][ty + r];
}

// ---------------- router: fp32 logits -> softmax -> top-2 -> renorm ----------------
__global__ void router_kernel(const float* __restrict__ X, const float* __restrict__ RW,
                              int* __restrict__ tok_e, float* __restrict__ tok_w) {
    const int lane = threadIdx.x & 63;
    const int wave = threadIdx.x >> 6;
    const int t = blockIdx.x * 4 + wave;
    const float* xp = X + (size_t)t * H_DIM;
    float xr[16];
#pragma unroll
    for (int j = 0; j < 16; ++j) xr[j] = xp[j * 64 + lane];
    float logits[E_NUM];
#pragma unroll
    for (int e = 0; e < E_NUM; ++e) {
        const float* rp = RW + e * H_DIM;
        float a = 0.f;
#pragma unroll
        for (int j = 0; j < 16; ++j) a += xr[j] * rp[j * 64 + lane];
#pragma unroll
        for (int s = 32; s; s >>= 1) a += __shfl_xor(a, s, 64);
        logits[e] = a;
    }
    if (lane == 0) {
        float mx = logits[0];
#pragma unroll
        for (int e = 1; e < E_NUM; ++e) mx = fmaxf(mx, logits[e]);
        float p[E_NUM], sum = 0.f;
#pragma unroll
        for (int e = 0; e < E_NUM; ++e) { p[e] = __expf(logits[e] - mx); sum += p[e]; }
#pragma unroll
        for (int e = 0; e < E_NUM; ++e) p[e] /= sum;
        int i0 = 0;
#pragma unroll
        for (int e = 1; e < E_NUM; ++e) if (p[e] > p[i0]) i0 = e;  // ties -> lowest idx
        int i1 = (i0 == 0) ? 1 : 0;
#pragma unroll
        for (int e = 0; e < E_NUM; ++e) if (e != i0 && p[e] > p[i1]) i1 = e;
        const float s2 = p[i0] + p[i1];
        tok_e[t * 2 + 0] = i0; tok_w[t * 2 + 0] = p[i0] / s2;
        tok_e[t * 2 + 1] = i1; tok_w[t * 2 + 1] = p[i1] / s2;
    }
}

// ---------------- build per-expert assignment lists + tile metadata (1 block) ----------------
__global__ void build_assignments(const int* __restrict__ tok_e, const float* __restrict__ tok_w,
                                  int* __restrict__ asg_tok, float* __restrict__ asg_wt,
                                  int* __restrict__ tok_slot, int* __restrict__ tile_meta,
                                  int* __restrict__ n_tiles_out) {
    __shared__ int cnt[E_NUM];
    __shared__ int seg_start[E_NUM];
    __shared__ int seg_pad[E_NUM];
    const int tid = threadIdx.x;
    if (tid < E_NUM) cnt[tid] = 0;
    __syncthreads();
    for (int i = tid; i < T_TOK * 2; i += 1024) atomicAdd(&cnt[tok_e[i]], 1);
    __syncthreads();
    if (tid == 0) {
        int run = 0, nt = 0;
        for (int e = 0; e < E_NUM; ++e) {
            seg_start[e] = run;
            const int tiles = (cnt[e] + 127) >> 7;
            seg_pad[e] = tiles << 7;
            for (int j = 0; j < tiles; ++j) {
                tile_meta[nt * 2] = e;
                tile_meta[nt * 2 + 1] = run + j * 128;
                ++nt;
            }
            run += tiles << 7;
        }
        *n_tiles_out = nt;
    }
    __syncthreads();
    if (tid < E_NUM) cnt[tid] = 0;
    __syncthreads();
    for (int i = tid; i < T_TOK * 2; i += 1024) {
        const int e = tok_e[i];
        const int slot = atomicAdd(&cnt[e], 1);
        const int g = seg_start[e] + slot;
        asg_tok[g] = i >> 1;
        asg_wt[g] = tok_w[i];
        tok_slot[i] = g;
    }
    __syncthreads();
    for (int e = 0; e < E_NUM; ++e)
        for (int j = cnt[e] + tid; j < seg_pad[e]; j += 1024) {
            asg_tok[seg_start[e] + j] = -1;
            asg_wt[seg_start[e] + j] = 0.f;
        }
}

// LDS swizzle: global chunk q of tile row r lives at slot (q + (r>>1))&3 within the row.
// Staged chunk for staging thread: c = (slot - (srow>>1))&3 with slot = tid&3, srow = tid>>2.
// Fragment reads then hit each bank exactly 2x per 16-lane phase (2-way = free, m136).

// ---------------- grouped GEMM1 (dual-acc GLU), 2-phase double-buffered pipeline ----------
// T3 minimum-2-phase: stage(next buf) -> ds_read(cur) -> MFMA (setprio) -> vmcnt(0)+s_barrier.
// One barrier per K-step (was 2 full __syncthreads drains); staging latency hides under MFMA.
__global__ __launch_bounds__(256, 2)
void gemm1_glu(const bf16_t* __restrict__ X, const bf16_t* __restrict__ W1all,
               const bf16_t* __restrict__ V1all, const int* __restrict__ asg_tok,
               const float* __restrict__ asg_wt, const int* __restrict__ tile_meta,
               const int* __restrict__ n_tiles, bf16_t* __restrict__ Hmid) {
    // T1 XCD swizzle: physical blocks with lin%8==k land on XCD k; give each XCD a
    // contiguous chunk of work ids (tile-fastest) so a dual W1/V1 panel stays L2-hot
    // for the ~17 consecutive tiles of one expert. nwg = 136*28 = 3808, %8 == 0.
    const int lin = blockIdx.x + MAX_TILES * blockIdx.y;
    const int w = (lin & 7) * (MAX_TILES * 28 / 8) + (lin >> 3);
    const int tile = w % MAX_TILES;
    const int nb = w / MAX_TILES;
    if (tile >= *n_tiles) return;
    const int e = tile_meta[tile * 2];
    const int row0 = tile_meta[tile * 2 + 1];
    const bf16_t* W1 = W1all + (size_t)e * F_DIM * H_DIM;
    const bf16_t* V1 = V1all + (size_t)e * F_DIM * H_DIM;

    __shared__ __attribute__((aligned(16))) bf16_t As[2][128 * 32];
    __shared__ __attribute__((aligned(16))) bf16_t B1s[2][128 * 32];
    __shared__ __attribute__((aligned(16))) bf16_t B2s[2][128 * 32];
    const int tid = threadIdx.x;
    const int lane = tid & 63;
    const int wave = tid >> 6;
    const int n0 = nb * 128;
    const int wm = (wave >> 1) * 64;
    const int wn = (wave & 1) * 64;
    const int fr = lane & 15;
    const int q = lane >> 4;

    floatx4 acc1[4][4], acc2[4][4];
    const floatx4 zero = {0.f, 0.f, 0.f, 0.f};
#pragma unroll
    for (int a = 0; a < 4; ++a)
#pragma unroll
        for (int b = 0; b < 4; ++b) { acc1[a][b] = zero; acc2[a][b] = zero; }

    const int srow = tid >> 2;
    const int c = ((tid & 3) - ((tid >> 3) & 3)) & 3;  // swizzled source chunk
    const int scc = c * 8;                             // bf16 column offset
    const int ldsb0 = (tid & 192) * 16;
    const int ldsb1 = 4096 + ldsb0;

    int t0 = asg_tok[row0 + srow];      if (t0 < 0) t0 = 0;
    int t1 = asg_tok[row0 + 64 + srow]; if (t1 < 0) t1 = 0;
    const bf16_t* a0p = X + (size_t)t0 * H_DIM + scc;
    const bf16_t* a1p = X + (size_t)t1 * H_DIM + scc;
    const bf16_t* b1p0 = W1 + (size_t)(n0 + srow) * H_DIM + scc;
    const bf16_t* b1p1 = W1 + (size_t)(n0 + 64 + srow) * H_DIM + scc;
    const bf16_t* b2p0 = V1 + (size_t)(n0 + srow) * H_DIM + scc;
    const bf16_t* b2p1 = V1 + (size_t)(n0 + 64 + srow) * H_DIM + scc;

    const int NT = H_DIM / 32;  // 32 K-steps

    // prologue: stage K-step 0 into buffer 0, drain, barrier
    async_copy16(a0p,  (char*)As[0]  + ldsb0);
    async_copy16(a1p,  (char*)As[0]  + ldsb1);
    async_copy16(b1p0, (char*)B1s[0] + ldsb0);
    async_copy16(b1p1, (char*)B1s[0] + ldsb1);
    async_copy16(b2p0, (char*)B2s[0] + ldsb0);
    async_copy16(b2p1, (char*)B2s[0] + ldsb1);
    WAIT_VM0();
    BAR();

    for (int t = 0; t < NT; ++t) {
        const int cur = t & 1;
        if (t + 1 < NT) {
            const int k = (t + 1) * 32;
            async_copy16(a0p + k,  (char*)As[cur ^ 1]  + ldsb0);
            async_copy16(a1p + k,  (char*)As[cur ^ 1]  + ldsb1);
            async_copy16(b1p0 + k, (char*)B1s[cur ^ 1] + ldsb0);
            async_copy16(b1p1 + k, (char*)B1s[cur ^ 1] + ldsb1);
            async_copy16(b2p0 + k, (char*)B2s[cur ^ 1] + ldsb0);
            async_copy16(b2p1 + k, (char*)B2s[cur ^ 1] + ldsb1);
        }
        __builtin_amdgcn_sched_barrier(0);  // pin stage-issue before frag reads

        const bf16_t* Ar  = As[cur];
        const bf16_t* B1r = B1s[cur];
        const bf16_t* B2r = B2s[cur];
        bf16x8 af[4], b1f[4], b2f[4];
#pragma unroll
        for (int mi = 0; mi < 4; ++mi) {
            const int r = wm + mi * 16 + fr;
            const int sl = (q + ((r >> 1) & 3)) & 3;
            af[mi] = *(const bf16x8*)&Ar[r * 32 + sl * 8];
        }
#pragma unroll
        for (int ni = 0; ni < 4; ++ni) {
            const int r = wn + ni * 16 + fr;
            const int sl = (q + ((r >> 1) & 3)) & 3;
            b1f[ni] = *(const bf16x8*)&B1r[r * 32 + sl * 8];
            b2f[ni] = *(const bf16x8*)&B2r[r * 32 + sl * 8];
        }
        __builtin_amdgcn_s_setprio(1);
#pragma unroll
        for (int mi = 0; mi < 4; ++mi)
#pragma unroll
            for (int ni = 0; ni < 4; ++ni) {
                acc1[mi][ni] = __builtin_amdgcn_mfma_f32_16x16x32_bf16(af[mi], b1f[ni], acc1[mi][ni], 0, 0, 0);
                acc2[mi][ni] = __builtin_amdgcn_mfma_f32_16x16x32_bf16(af[mi], b2f[ni], acc2[mi][ni], 0, 0, 0);
            }
        __builtin_amdgcn_s_setprio(0);
        if (t + 1 < NT) {
            WAIT_VM0();  // this iteration's 6 stage-loads had the whole MFMA phase in flight
            BAR();
        }
    }

    // epilogue: C layout col = lane&15, row = q*4 + reg
#pragma unroll
    for (int mi = 0; mi < 4; ++mi) {
#pragma unroll
        for (int r = 0; r < 4; ++r) {
            const int gr = row0 + wm + mi * 16 + q * 4 + r;
            const float wt = asg_wt[gr];
            bf16_t* hp = Hmid + (size_t)gr * F_DIM + n0 + wn + fr;
#pragma unroll
            for (int ni = 0; ni < 4; ++ni) {
                const float s1 = acc1[mi][ni][r];
                const float s2 = acc2[mi][ni][r];
                const float val = (s1 / (1.f + __expf(-s1))) * s2 * wt;
                hp[ni * 16] = (bf16_t)val;
            }
        }
    }
}

// ---------------- grouped GEMM2, same 2-phase pipeline: oasm[g] = hmid[g] @ W2[e] ----------
__global__ __launch_bounds__(256, 2)
void gemm2_out(const bf16_t* __restrict__ Hmid, const bf16_t* __restrict__ W2Tall,
               const int* __restrict__ tile_meta, const int* __restrict__ n_tiles,
               float* __restrict__ Oasm) {
    // T1 XCD swizzle, n0-fastest work order: each XCD owns 17 contiguous hmid tiles
    // (the 125 MB stream gets partitioned, read ~once per XCD); a 0.9 MB hmid A-tile
    // stays L2-hot across its 8 consecutive n0 blocks. nwg = 136*8, q = 136.
    const int lin = blockIdx.x + MAX_TILES * blockIdx.y;
    const int w = (lin & 7) * MAX_TILES + (lin >> 3);
    const int tile = w >> 3;
    const int n0 = (w & 7) * 128;
    if (tile >= *n_tiles) return;
    const int e = tile_meta[tile * 2];
    const int row0 = tile_meta[tile * 2 + 1];
    const bf16_t* W2T = W2Tall + (size_t)e * H_DIM * F_DIM;

    __shared__ __attribute__((aligned(16))) bf16_t As[2][128 * 32];
    __shared__ __attribute__((aligned(16))) bf16_t Bs[2][128 * 32];
    const int tid = threadIdx.x;
    const int lane = tid & 63;
    const int wave = tid >> 6;
    const int wm = (wave >> 1) * 64;
    const int wn = (wave & 1) * 64;
    const int fr = lane & 15;
    const int q = lane >> 4;

    floatx4 acc[4][4];
    const floatx4 zero = {0.f, 0.f, 0.f, 0.f};
#pragma unroll
    for (int a = 0; a < 4; ++a)
#pragma unroll
        for (int b = 0; b < 4; ++b) acc[a][b] = zero;

    const int srow = tid >> 2;
    const int c = ((tid & 3) - ((tid >> 3) & 3)) & 3;
    const int scc = c * 8;
    const int ldsb0 = (tid & 192) * 16;
    const int ldsb1 = 4096 + ldsb0;

    const bf16_t* a0p = Hmid + (size_t)(row0 + srow) * F_DIM + scc;
    const bf16_t* a1p = Hmid + (size_t)(row0 + 64 + srow) * F_DIM + scc;
    const bf16_t* b0p = W2T + (size_t)(n0 + srow) * F_DIM + scc;
    const bf16_t* b1p = W2T + (size_t)(n0 + 64 + srow) * F_DIM + scc;

    const int NT = F_DIM / 32;  // 112 K-steps

    async_copy16(a0p, (char*)As[0] + ldsb0);
    async_copy16(a1p, (char*)As[0] + ldsb1);
    async_copy16(b0p, (char*)Bs[0] + ldsb0);
    async_copy16(b1p, (char*)Bs[0] + ldsb1);
    WAIT_VM0();
    BAR();

    for (int t = 0; t < NT; ++t) {
        const int cur = t & 1;
        if (t + 1 < NT) {
            const int k = (t + 1) * 32;
            async_copy16(a0p + k, (char*)As[cur ^ 1] + ldsb0);
            async_copy16(a1p + k, (char*)As[cur ^ 1] + ldsb1);
            async_copy16(b0p + k, (char*)Bs[cur ^ 1] + ldsb0);
            async_copy16(b1p + k, (char*)Bs[cur ^ 1] + ldsb1);
        }
        __builtin_amdgcn_sched_barrier(0);

        const bf16_t* Ar = As[cur];
        const bf16_t* Br = Bs[cur];
        bf16x8 af[4], bf[4];
#pragma unroll
        for (int mi = 0; mi < 4; ++mi) {
            const int r = wm + mi * 16 + fr;
            const int sl = (q + ((r >> 1) & 3)) & 3;
            af[mi] = *(const bf16x8*)&Ar[r * 32 + sl * 8];
        }
#pragma unroll
        for (int ni = 0; ni < 4; ++ni) {
            const int r = wn + ni * 16 + fr;
            const int sl = (q + ((r >> 1) & 3)) & 3;
            bf[ni] = *(const bf16x8*)&Br[r * 32 + sl * 8];
        }
        __builtin_amdgcn_s_setprio(1);
#pragma unroll
        for (int mi = 0; mi < 4; ++mi)
#pragma unroll
            for (int ni = 0; ni < 4; ++ni)
                acc[mi][ni] = __builtin_amdgcn_mfma_f32_16x16x32_bf16(af[mi], bf[ni], acc[mi][ni], 0, 0, 0);
        __builtin_amdgcn_s_setprio(0);
        if (t + 1 < NT) {
            WAIT_VM0();
            BAR();
        }
    }

#pragma unroll
    for (int mi = 0; mi < 4; ++mi) {
#pragma unroll
        for (int r = 0; r < 4; ++r) {
            const int gr = row0 + wm + mi * 16 + q * 4 + r;
            float* op = Oasm + (size_t)gr * H_DIM + n0 + wn + fr;
#pragma unroll
            for (int ni = 0; ni < 4; ++ni)
                op[ni * 16] = acc[mi][ni][r];
        }
    }
}

// ---------------- combine: out[t] = oasm[slot0(t)] + oasm[slot1(t)]  (deterministic) ---------
__global__ void combine_kernel(const float* __restrict__ Oasm, const int* __restrict__ tok_slot,
                               float* __restrict__ Out) {
    const int t = blockIdx.x;
    const int s0 = tok_slot[t * 2];
    const int s1 = tok_slot[t * 2 + 1];
    const float4 v0 = ((const float4*)(Oasm + (size_t)s0 * H_DIM))[threadIdx.x];
    const float4 v1 = ((const float4*)(Oasm + (size_t)s1 * H_DIM))[threadIdx.x];
    float4 o; o.x = v0.x + v1.x; o.y = v0.y + v1.y; o.z = v0.z + v1.z; o.w = v0.w + v1.w;
    ((float4*)(Out + (size_t)t * H_DIM))[threadIdx.x] = o;
}

extern "C" void kernel_launch(void* const* d_in, const int* in_sizes, int n_in,
                              void* d_out, int out_size, void* d_ws, size_t ws_size,
                              hipStream_t stream) {
    const float* x  = (const float*)d_in[0];   // [T, H] fp32
    const float* rw = (const float*)d_in[1];   // [E, H] fp32
    const float* w1 = (const float*)d_in[2];   // [E, F, H] fp32
    const float* v1 = (const float*)d_in[3];   // [E, F, H] fp32
    const float* w2 = (const float*)d_in[4];   // [E, F, H] fp32
    float* out = (float*)d_out;                // [T, H] fp32

    // workspace layout (byte offsets). Phase-1 live: xb, w1b, v1b, hmid.
    // Phase-2 live: w2t (aliases xb + w1b head), oasm (aliases w1b tail + v1b), hmid.
    char* ws = (char*)d_ws;
    const size_t MB = 1024 * 1024;
    bf16_t* xb   = (bf16_t*)(ws + 0);          // 16 MiB [0, 16)
    bf16_t* w1b  = (bf16_t*)(ws + 16 * MB);    // 56 MiB [16, 72)
    bf16_t* v1b  = (bf16_t*)(ws + 72 * MB);    // 56 MiB [72, 128)
    bf16_t* hmid = (bf16_t*)(ws + 128 * MB);   // 119 MiB [128, 247.01)
    bf16_t* w2t  = (bf16_t*)(ws + 0);          // 56 MiB [0, 56)   (after gemm1)
    float*  oasm = (float*)(ws + 56 * MB);     // 68 MiB [56, 124) (after gemm1)
    char* meta = ws + 128 * MB + (size_t)MAX_ROWS * F_DIM * 2;
    int*   asg_tok  = (int*)meta;                meta += MAX_ROWS * 4;
    float* asg_wt   = (float*)meta;              meta += MAX_ROWS * 4;
    int*   tok_slot = (int*)meta;                meta += T_TOK * 2 * 4;
    int*   tok_e    = (int*)meta;                meta += T_TOK * 2 * 4;
    float* tok_w    = (float*)meta;              meta += T_TOK * 2 * 4;
    int*   tile_meta = (int*)meta;               meta += MAX_TILES * 2 * 4;
    int*   n_tiles   = (int*)meta;               meta += 4;

    const int nx4 = T_TOK * H_DIM / 4;
    const int nw4 = E_NUM * F_DIM * H_DIM / 4;
    cast_f32_to_bf16<<<nx4 / 256, 256, 0, stream>>>(x, xb, nx4);
    cast_f32_to_bf16<<<nw4 / 256, 256, 0, stream>>>(w1, w1b, nw4);
    cast_f32_to_bf16<<<nw4 / 256, 256, 0, stream>>>(v1, v1b, nw4);
    router_kernel<<<T_TOK / 4, 256, 0, stream>>>(x, rw, tok_e, tok_w);
    build_assignments<<<1, 1024, 0, stream>>>(tok_e, tok_w, asg_tok, asg_wt,
                                              tok_slot, tile_meta, n_tiles);
    gemm1_glu<<<dim3(MAX_TILES, F_DIM / 128), 256, 0, stream>>>(
        xb, w1b, v1b, asg_tok, asg_wt, tile_meta, n_tiles, hmid);
    // w1b/v1b/xb dead from here; build w2t over them
    transpose_cast_w2<<<dim3(F_DIM / 32, H_DIM / 32, E_NUM), dim3(32, 8), 0, stream>>>(w2, w2t);
    gemm2_out<<<dim3(MAX_TILES, H_DIM / 128), 256, 0, stream>>>(
        hmid, w2t, tile_meta, n_tiles, oasm);
    combine_kernel<<<T_TOK, 256, 0, stream>>>(oasm, tok_slot, out);
}

// Round 2
// 889.942 us; speedup vs baseline: 1.0406x; 1.0359x over previous
//
#include <hip/hip_runtime.h>
#include <cstdint>
#include <cstddef>

// Problem constants (B=4, S=2048 -> T=8192 tokens)
#define T_TOK 8192
#define H_DIM 1024
#define F_DIM 3584
#define E_NUM 8
#define MAX_ROWS 18432   // 72 tiles * 256 rows (2T assignments, per-expert pad to 256)
#define MAX_T256 72      // worst-case 256-row tiles
#define MAX_T128 144     // worst-case 128-row tiles (gemm2)
#define NB1 28           // 2F/256 = Bcat n-blocks for gemm1 (=128 output f-cols each)

typedef __bf16 bf16_t;
typedef bf16_t bf16x8 __attribute__((ext_vector_type(8)));
typedef bf16_t bf16x4 __attribute__((ext_vector_type(4)));
typedef float floatx4 __attribute__((ext_vector_type(4)));

typedef const __attribute__((address_space(1))) void* gas_ptr;
typedef __attribute__((address_space(3))) void* las_ptr;

__device__ __forceinline__ void async_copy16(const void* g, void* l) {
    __builtin_amdgcn_global_load_lds((gas_ptr)g, (las_ptr)l, 16, 0, 0);
}

#define SB0() __builtin_amdgcn_sched_barrier(0)
#define WAIT_VM0() asm volatile("s_waitcnt vmcnt(0)" ::: "memory")
#define BAR() __builtin_amdgcn_s_barrier()

// ---------------- elementwise fp32 -> bf16 cast (x only) ----------------
__global__ void cast_f32_to_bf16(const float* __restrict__ in, bf16_t* __restrict__ out, int n4) {
    int i = blockIdx.x * blockDim.x + threadIdx.x;
    if (i < n4) {
        const float4 v = ((const float4*)in)[i];
        bf16x4 o;
        o[0] = (bf16_t)v.x; o[1] = (bf16_t)v.y; o[2] = (bf16_t)v.z; o[3] = (bf16_t)v.w;
        ((bf16x4*)out)[i] = o;
    }
}

// ---------------- w1/v1 fp32 -> Bcat bf16, 16-row interleave ----------------
// Bcat[e] row layout: rows [32j,32j+16) = W1 f-rows [16j,16j+16); [32j+16,32j+32) = V1 same.
// => in a 256-row n-block, N-frag pairs (2f,2f+1) hold (W1,V1) for the SAME output cols.
__global__ void cast_interleave_glu(const float* __restrict__ W1, const float* __restrict__ V1,
                                    bf16_t* __restrict__ Bcat, int n4) {
    int i = blockIdx.x * blockDim.x + threadIdx.x;
    if (i >= n4) return;
    const int HQ = H_DIM / 4;
    const int h4 = i & (HQ - 1);
    const int rest = i >> 8;          // HQ = 256
    const int f = rest % F_DIM;
    const int e = rest / F_DIM;
    const size_t dst = ((size_t)e * (2 * F_DIM) + 32 * (f >> 4) + (f & 15)) * H_DIM + h4 * 4;
    const float4 a = ((const float4*)W1)[i];
    const float4 b = ((const float4*)V1)[i];
    bf16x4 oa, ob;
    oa[0] = (bf16_t)a.x; oa[1] = (bf16_t)a.y; oa[2] = (bf16_t)a.z; oa[3] = (bf16_t)a.w;
    ob[0] = (bf16_t)b.x; ob[1] = (bf16_t)b.y; ob[2] = (bf16_t)b.z; ob[3] = (bf16_t)b.w;
    *(bf16x4*)(Bcat + dst) = oa;
    *(bf16x4*)(Bcat + dst + (size_t)16 * H_DIM) = ob;
}

// ---------------- w2 [E,F,H] fp32 -> w2t [E,H,F] bf16 (tiled transpose) ----------------
__global__ void transpose_cast_w2(const float* __restrict__ W2, bf16_t* __restrict__ W2T) {
    __shared__ bf16_t tile[32][34];
    const int e = blockIdx.z;
    const int f0 = blockIdx.x * 32;
    const int h0 = blockIdx.y * 32;
    const float* src = W2 + (size_t)e * F_DIM * H_DIM;
    bf16_t* dst = W2T + (size_t)e * H_DIM * F_DIM;
    const int tx = threadIdx.x;
    const int ty = threadIdx.y;
#pragma unroll
    for (int r = 0; r < 32; r += 8)
        tile[ty + r][tx] = (bf16_t)src[(size_t)(f0 + ty + r) * H_DIM + (h0 + tx)];
    __syncthreads();
#pragma unroll
    for (int r = 0; r < 32; r += 8)
        dst[(size_t)(h0 + ty + r) * F_DIM + (f0 + tx)] = tile[tx][ty + r];
}

// ---------------- router: fp32 logits -> softmax -> top-2 -> renorm ----------------
__global__ void router_kernel(const float* __restrict__ X, const float* __restrict__ RW,
                              int* __restrict__ tok_e, float* __restrict__ tok_w) {
    const int lane = threadIdx.x & 63;
    const int wave = threadIdx.x >> 6;
    const int t = blockIdx.x * 4 + wave;
    const float* xp = X + (size_t)t * H_DIM;
    float xr[16];
#pragma unroll
    for (int j = 0; j < 16; ++j) xr[j] = xp[j * 64 + lane];
    float logits[E_NUM];
#pragma unroll
    for (int e = 0; e < E_NUM; ++e) {
        const float* rp = RW + e * H_DIM;
        float a = 0.f;
#pragma unroll
        for (int j = 0; j < 16; ++j) a += xr[j] * rp[j * 64 + lane];
#pragma unroll
        for (int s = 32; s; s >>= 1) a += __shfl_xor(a, s, 64);
        logits[e] = a;
    }
    if (lane == 0) {
        float mx = logits[0];
#pragma unroll
        for (int e = 1; e < E_NUM; ++e) mx = fmaxf(mx, logits[e]);
        float p[E_NUM], sum = 0.f;
#pragma unroll
        for (int e = 0; e < E_NUM; ++e) { p[e] = __expf(logits[e] - mx); sum += p[e]; }
#pragma unroll
        for (int e = 0; e < E_NUM; ++e) p[e] /= sum;
        int i0 = 0;
#pragma unroll
        for (int e = 1; e < E_NUM; ++e) if (p[e] > p[i0]) i0 = e;
        int i1 = (i0 == 0) ? 1 : 0;
#pragma unroll
        for (int e = 0; e < E_NUM; ++e) if (e != i0 && p[e] > p[i1]) i1 = e;
        const float s2 = p[i0] + p[i1];
        tok_e[t * 2 + 0] = i0; tok_w[t * 2 + 0] = p[i0] / s2;
        tok_e[t * 2 + 1] = i1; tok_w[t * 2 + 1] = p[i1] / s2;
    }
}

// ---------------- build per-expert assignment lists + two tile metadatas (1 block) ----------
__global__ void build_assignments(const int* __restrict__ tok_e, const float* __restrict__ tok_w,
                                  int* __restrict__ asg_tok, float* __restrict__ asg_wt,
                                  int* __restrict__ tok_slot,
                                  int* __restrict__ tm256, int* __restrict__ n256,
                                  int* __restrict__ tm128, int* __restrict__ n128) {
    __shared__ int cnt[E_NUM];
    __shared__ int seg_start[E_NUM];
    __shared__ int seg_pad[E_NUM];
    const int tid = threadIdx.x;
    if (tid < E_NUM) cnt[tid] = 0;
    __syncthreads();
    for (int i = tid; i < T_TOK * 2; i += 1024) atomicAdd(&cnt[tok_e[i]], 1);
    __syncthreads();
    if (tid == 0) {
        int run = 0, a = 0, b = 0;
        for (int e = 0; e < E_NUM; ++e) {
            seg_start[e] = run;
            const int t256 = (cnt[e] + 255) >> 8;
            seg_pad[e] = t256 << 8;
            for (int j = 0; j < t256; ++j) { tm256[a * 2] = e; tm256[a * 2 + 1] = run + j * 256; ++a; }
            for (int j = 0; j < t256 * 2; ++j) { tm128[b * 2] = e; tm128[b * 2 + 1] = run + j * 128; ++b; }
            run += t256 << 8;
        }
        *n256 = a; *n128 = b;
    }
    __syncthreads();
    if (tid < E_NUM) cnt[tid] = 0;
    __syncthreads();
    for (int i = tid; i < T_TOK * 2; i += 1024) {
        const int e = tok_e[i];
        const int slot = atomicAdd(&cnt[e], 1);
        const int g = seg_start[e] + slot;
        asg_tok[g] = i >> 1;
        asg_wt[g] = tok_w[i];
        tok_slot[i] = g;
    }
    __syncthreads();
    for (int e = 0; e < E_NUM; ++e)
        for (int j = cnt[e] + tid; j < seg_pad[e]; j += 1024) {
            asg_tok[seg_start[e] + j] = -1;
            asg_wt[seg_start[e] + j] = 0.f;
        }
}

// ================= gemm1: 256x256 8-phase counted-vmcnt template (T3+T4+T5+T1+T2) =========
// Tile: BM=256 assignment rows x 256 Bcat rows (=128 W1 + 128 V1 f-cols), BK=64, 8 waves.
// LDS 128 KiB: A[slot][half] @ slot*32768+half*16384 ; B @ 65536+... ; slot = ktile&1.
// Per iter (2 K-tiles): 8 phases {ds_read quadrant || stage half-tile -> bar -> lgkm0 ->
// setprio 16xMFMA -> bar}. Counted waits: vmcnt(4) @ph4, vmcnt(8) @ph8 (derived for stage
// order B0',B0',A0',A0',B1'x2,A1'x2). XOR chunk swizzle c^=(row&7) on both stage-src + read.
__global__ __launch_bounds__(512, 2)
void gemm1_glu(const bf16_t* __restrict__ X, const bf16_t* __restrict__ Bcat,
               const int* __restrict__ asg_tok, const float* __restrict__ asg_wt,
               const int* __restrict__ tile_meta, const int* __restrict__ n_tiles,
               bf16_t* __restrict__ Hmid) {
    // T1: XCD-contiguous work chunks, tile-fastest (expert weight panel per nb = 4MB ~ L2)
    const int lin = blockIdx.x + MAX_T256 * blockIdx.y;
    const int w = (lin & 7) * (MAX_T256 * NB1 / 8) + (lin >> 3);
    const int tile = w % MAX_T256;
    const int nb = w / MAX_T256;
    if (tile >= *n_tiles) return;
    const int e = tile_meta[tile * 2];
    const int row0 = tile_meta[tile * 2 + 1];

    __shared__ __attribute__((aligned(16))) char lds[131072];

    const int tid = threadIdx.x;
    const int lane = tid & 63;
    const int wave = tid >> 6;
    const int wm = wave >> 2;      // 2 M halves
    const int wn = wave & 3;       // 4 N quarters
    const int fr = lane & 15;
    const int q = lane >> 4;

    // staging: thread covers 4 rows (j*64 + tid>>3) of A and B, one 16B chunk each
    const int srow = tid >> 3;                       // 0..63
    const int cA = (tid & 7) ^ (srow & 7);           // XOR chunk swizzle (store side)
    const int ldsWave = wave * 1024;                 // wave-uniform dest base

    const bf16_t* pA[4];
    const bf16_t* pB[4];
#pragma unroll
    for (int j = 0; j < 4; ++j) {
        int t = asg_tok[row0 + j * 64 + srow]; if (t < 0) t = 0;
        pA[j] = X + (size_t)t * H_DIM + cA * 8;
        pB[j] = Bcat + ((size_t)e * (2 * F_DIM) + (size_t)(nb * 256 + j * 64 + srow)) * H_DIM + cA * 8;
    }

#define STG_A(slot, half, ktEl) do { \
    async_copy16(pA[(half)*2+0] + (ktEl), lds + (slot)*32768 + (half)*16384 + ldsWave); \
    async_copy16(pA[(half)*2+1] + (ktEl), lds + (slot)*32768 + (half)*16384 + 8192 + ldsWave); \
  } while (0)
#define STG_B(slot, half, ktEl) do { \
    async_copy16(pB[(half)*2+0] + (ktEl), lds + 65536 + (slot)*32768 + (half)*16384 + ldsWave); \
    async_copy16(pB[(half)*2+1] + (ktEl), lds + 65536 + (slot)*32768 + (half)*16384 + 8192 + ldsWave); \
  } while (0)

    // read-side addressing (XOR swizzle on chunk)
    const int aRow = wm * 16384 + fr * 128;
    const int bRow = 65536 + (wn >> 1) * 16384 + ((wn & 1) * 64 + fr) * 128;
    int cOff[2];
    cOff[0] = ((0 * 4 + q) ^ (fr & 7)) << 4;
    cOff[1] = ((1 * 4 + q) ^ (fr & 7)) << 4;

#define LDA(slot, mi, ks) (*(const bf16x8*)(lds + (slot)*32768 + aRow + (mi)*2048 + cOff[ks]))
#define LDB(slot, ni, ks) (*(const bf16x8*)(lds + (slot)*32768 + bRow + (ni)*2048 + cOff[ks]))

    floatx4 acc[8][4];
    const floatx4 zero = {0.f, 0.f, 0.f, 0.f};
#pragma unroll
    for (int m = 0; m < 8; ++m)
#pragma unroll
        for (int n = 0; n < 4; ++n) acc[m][n] = zero;

    bf16x8 a[8], bn0[4], bn1[4];

#define PH_PRE() do { SB0(); BAR(); \
    asm volatile("s_waitcnt lgkmcnt(0)" ::: "memory"); SB0(); } while (0)
#define PH_POST() do { SB0(); BAR(); SB0(); } while (0)
#define MF16(mq, nq, BREG) do { \
    __builtin_amdgcn_s_setprio(1); \
    _Pragma("unroll") for (int ml = 0; ml < 4; ++ml) \
    _Pragma("unroll") for (int nl = 0; nl < 2; ++nl) \
    _Pragma("unroll") for (int ks = 0; ks < 2; ++ks) \
        acc[(mq)*4+ml][(nq)*2+nl] = __builtin_amdgcn_mfma_f32_16x16x32_bf16( \
            a[ml*2+ks], BREG[nl*2+ks], acc[(mq)*4+ml][(nq)*2+nl], 0, 0, 0); \
    __builtin_amdgcn_s_setprio(0); \
  } while (0)

    // prologue: stage K-tiles 0 (slot0) then 1 (slot1); first-8 = slot0 -> vmcnt(8)
    STG_B(0, 0, 0); STG_B(0, 1, 0); STG_A(0, 0, 0); STG_A(0, 1, 0);
    STG_B(1, 0, 64); STG_B(1, 1, 64); STG_A(1, 0, 64); STG_A(1, 1, 64);
    asm volatile("s_waitcnt vmcnt(8)" ::: "memory");
    BAR(); SB0();

#pragma unroll 1
    for (int i = 0; i < 8; ++i) {              // 8 iters x 2 K-tiles x 64 = K=1024
        const bool stg = (i < 7);
        const int k0e = (2 * i + 2) * 64;      // element offset of tile 2i+2
        const int k1e = k0e + 64;              // tile 2i+3

        // ---- phase 1: slot0 (mq0,nq0); reads A mq0 + B nq0 (12 ds_read)
#pragma unroll
        for (int ml = 0; ml < 4; ++ml) { a[ml*2+0] = LDA(0, ml, 0); a[ml*2+1] = LDA(0, ml, 1); }
#pragma unroll
        for (int nl = 0; nl < 2; ++nl) { bn0[nl*2+0] = LDB(0, nl, 0); bn0[nl*2+1] = LDB(0, nl, 1); }
        PH_PRE(); MF16(0, 0, bn0); PH_POST();

        // ---- phase 2: (mq0,nq1); reads B nq1 (4)
#pragma unroll
        for (int nl = 0; nl < 2; ++nl) { bn1[nl*2+0] = LDB(0, 2+nl, 0); bn1[nl*2+1] = LDB(0, 2+nl, 1); }
        PH_PRE(); MF16(0, 1, bn1); PH_POST();

        // ---- phase 3: (mq1,nq0); stage B0a' (slot0 B free after ph2); reads A mq1 (8)
        if (stg) STG_B(0, 0, k0e);
#pragma unroll
        for (int ml = 0; ml < 4; ++ml) { a[ml*2+0] = LDA(0, 4+ml, 0); a[ml*2+1] = LDA(0, 4+ml, 1); }
        PH_PRE(); MF16(1, 0, bn0); PH_POST();

        // ---- phase 4: (mq1,nq1); stage B0b'; counted vmcnt: all PREV-iter loads landed
        if (stg) STG_B(0, 1, k0e);
        PH_PRE(); MF16(1, 1, bn1);
        SB0();
        if (stg) asm volatile("s_waitcnt vmcnt(4)" ::: "memory");
        else     asm volatile("s_waitcnt vmcnt(0)" ::: "memory");
        BAR(); SB0();

        // ---- phase 5: slot1 (mq0,nq0); stage A0a' (slot0 A free after ph3)
        if (stg) STG_A(0, 0, k0e);
#pragma unroll
        for (int ml = 0; ml < 4; ++ml) { a[ml*2+0] = LDA(1, ml, 0); a[ml*2+1] = LDA(1, ml, 1); }
#pragma unroll
        for (int nl = 0; nl < 2; ++nl) { bn0[nl*2+0] = LDB(1, nl, 0); bn0[nl*2+1] = LDB(1, nl, 1); }
        PH_PRE(); MF16(0, 0, bn0); PH_POST();

        // ---- phase 6: (mq0,nq1); stage A0b'
        if (stg) STG_A(0, 1, k0e);
#pragma unroll
        for (int nl = 0; nl < 2; ++nl) { bn1[nl*2+0] = LDB(1, 2+nl, 0); bn1[nl*2+1] = LDB(1, 2+nl, 1); }
        PH_PRE(); MF16(0, 1, bn1); PH_POST();

        // ---- phase 7: (mq1,nq0); stage B1a'+B1b' (slot1 B free after ph6)
        if (stg) { STG_B(1, 0, k1e); STG_B(1, 1, k1e); }
#pragma unroll
        for (int ml = 0; ml < 4; ++ml) { a[ml*2+0] = LDA(1, 4+ml, 0); a[ml*2+1] = LDA(1, 4+ml, 1); }
        PH_PRE(); MF16(1, 0, bn0); PH_POST();

        // ---- phase 8: (mq1,nq1); stage A1a'+A1b' (slot1 A free after ph7); vmcnt(8)
        if (stg) { STG_A(1, 0, k1e); STG_A(1, 1, k1e); }
        PH_PRE(); MF16(1, 1, bn1);
        SB0();
        asm volatile("s_waitcnt vmcnt(8)" ::: "memory");
        BAR(); SB0();
    }

    // epilogue: in-register GLU. ni pair (2fb, 2fb+1) = (W1,V1) for f = nb*128+(2wn+fb)*16+fr
#pragma unroll
    for (int mi = 0; mi < 8; ++mi) {
#pragma unroll
        for (int rr = 0; rr < 4; ++rr) {
            const int gr = row0 + wm * 128 + mi * 16 + q * 4 + rr;
            const float wt = asg_wt[gr];
            bf16_t* hp = Hmid + (size_t)gr * F_DIM + nb * 128 + (2 * wn) * 16 + fr;
#pragma unroll
            for (int fb = 0; fb < 2; ++fb) {
                const float s1 = acc[mi][2 * fb][rr];
                const float s2 = acc[mi][2 * fb + 1][rr];
                hp[fb * 16] = (bf16_t)((s1 / (1.f + __expf(-s1))) * s2 * wt);
            }
        }
    }
#undef STG_A
#undef STG_B
#undef LDA
#undef LDB
#undef PH_PRE
#undef PH_POST
#undef MF16
}

// ---------------- grouped GEMM2, 2-phase pipeline (unchanged structure, 128-tiles) --------
__global__ __launch_bounds__(256, 2)
void gemm2_out(const bf16_t* __restrict__ Hmid, const bf16_t* __restrict__ W2Tall,
               const int* __restrict__ tile_meta, const int* __restrict__ n_tiles,
               float* __restrict__ Oasm) {
    const int lin = blockIdx.x + MAX_T128 * blockIdx.y;
    const int w = (lin & 7) * MAX_T128 + (lin >> 3);
    const int tile = w >> 3;
    const int n0 = (w & 7) * 128;
    if (tile >= *n_tiles) return;
    const int e = tile_meta[tile * 2];
    const int row0 = tile_meta[tile * 2 + 1];
    const bf16_t* W2T = W2Tall + (size_t)e * H_DIM * F_DIM;

    __shared__ __attribute__((aligned(16))) bf16_t As[2][128 * 32];
    __shared__ __attribute__((aligned(16))) bf16_t Bs[2][128 * 32];
    const int tid = threadIdx.x;
    const int lane = tid & 63;
    const int wave = tid >> 6;
    const int wm = (wave >> 1) * 64;
    const int wn = (wave & 1) * 64;
    const int fr = lane & 15;
    const int q = lane >> 4;

    floatx4 acc[4][4];
    const floatx4 zero = {0.f, 0.f, 0.f, 0.f};
#pragma unroll
    for (int a = 0; a < 4; ++a)
#pragma unroll
        for (int b = 0; b < 4; ++b) acc[a][b] = zero;

    const int srow = tid >> 2;
    const int c = ((tid & 3) - ((tid >> 3) & 3)) & 3;
    const int scc = c * 8;
    const int ldsb0 = (tid & 192) * 16;
    const int ldsb1 = 4096 + ldsb0;

    const bf16_t* a0p = Hmid + (size_t)(row0 + srow) * F_DIM + scc;
    const bf16_t* a1p = Hmid + (size_t)(row0 + 64 + srow) * F_DIM + scc;
    const bf16_t* b0p = W2T + (size_t)(n0 + srow) * F_DIM + scc;
    const bf16_t* b1p = W2T + (size_t)(n0 + 64 + srow) * F_DIM + scc;

    const int NT = F_DIM / 32;  // 112 K-steps

    async_copy16(a0p, (char*)As[0] + ldsb0);
    async_copy16(a1p, (char*)As[0] + ldsb1);
    async_copy16(b0p, (char*)Bs[0] + ldsb0);
    async_copy16(b1p, (char*)Bs[0] + ldsb1);
    WAIT_VM0();
    BAR();

    for (int t = 0; t < NT; ++t) {
        const int cur = t & 1;
        if (t + 1 < NT) {
            const int k = (t + 1) * 32;
            async_copy16(a0p + k, (char*)As[cur ^ 1] + ldsb0);
            async_copy16(a1p + k, (char*)As[cur ^ 1] + ldsb1);
            async_copy16(b0p + k, (char*)Bs[cur ^ 1] + ldsb0);
            async_copy16(b1p + k, (char*)Bs[cur ^ 1] + ldsb1);
        }
        __builtin_amdgcn_sched_barrier(0);

        const bf16_t* Ar = As[cur];
        const bf16_t* Br = Bs[cur];
        bf16x8 af[4], bf[4];
#pragma unroll
        for (int mi = 0; mi < 4; ++mi) {
            const int r = wm + mi * 16 + fr;
            const int sl = (q + ((r >> 1) & 3)) & 3;
            af[mi] = *(const bf16x8*)&Ar[r * 32 + sl * 8];
        }
#pragma unroll
        for (int ni = 0; ni < 4; ++ni) {
            const int r = wn + ni * 16 + fr;
            const int sl = (q + ((r >> 1) & 3)) & 3;
            bf[ni] = *(const bf16x8*)&Br[r * 32 + sl * 8];
        }
        __builtin_amdgcn_s_setprio(1);
#pragma unroll
        for (int mi = 0; mi < 4; ++mi)
#pragma unroll
            for (int ni = 0; ni < 4; ++ni)
                acc[mi][ni] = __builtin_amdgcn_mfma_f32_16x16x32_bf16(af[mi], bf[ni], acc[mi][ni], 0, 0, 0);
        __builtin_amdgcn_s_setprio(0);
        if (t + 1 < NT) {
            WAIT_VM0();
            BAR();
        }
    }

#pragma unroll
    for (int mi = 0; mi < 4; ++mi) {
#pragma unroll
        for (int r = 0; r < 4; ++r) {
            const int gr = row0 + wm + mi * 16 + q * 4 + r;
            float* op = Oasm + (size_t)gr * H_DIM + n0 + wn + fr;
#pragma unroll
            for (int ni = 0; ni < 4; ++ni)
                op[ni * 16] = acc[mi][ni][r];
        }
    }
}

// ---------------- combine: out[t] = oasm[slot0(t)] + oasm[slot1(t)] ----------------
__global__ void combine_kernel(const float* __restrict__ Oasm, const int* __restrict__ tok_slot,
                               float* __restrict__ Out) {
    const int t = blockIdx.x;
    const int s0 = tok_slot[t * 2];
    const int s1 = tok_slot[t * 2 + 1];
    const float4 v0 = ((const float4*)(Oasm + (size_t)s0 * H_DIM))[threadIdx.x];
    const float4 v1 = ((const float4*)(Oasm + (size_t)s1 * H_DIM))[threadIdx.x];
    float4 o; o.x = v0.x + v1.x; o.y = v0.y + v1.y; o.z = v0.z + v1.z; o.w = v0.w + v1.w;
    ((float4*)(Out + (size_t)t * H_DIM))[threadIdx.x] = o;
}

extern "C" void kernel_launch(void* const* d_in, const int* in_sizes, int n_in,
                              void* d_out, int out_size, void* d_ws, size_t ws_size,
                              hipStream_t stream) {
    const float* x  = (const float*)d_in[0];   // [T, H] fp32
    const float* rw = (const float*)d_in[1];   // [E, H] fp32
    const float* w1 = (const float*)d_in[2];   // [E, F, H] fp32
    const float* v1 = (const float*)d_in[3];   // [E, F, H] fp32
    const float* w2 = (const float*)d_in[4];   // [E, F, H] fp32
    float* out = (float*)d_out;                // [T, H] fp32

    // workspace layout. Phase-1 live: xb[0,16), bcat[16,128), hmid[128,254).
    // Phase-2 live: w2t[0,56), oasm[56,128), hmid. meta after hmid.
    char* ws = (char*)d_ws;
    const size_t MB = 1024 * 1024;
    bf16_t* xb   = (bf16_t*)(ws + 0);            // 16 MiB
    bf16_t* bcat = (bf16_t*)(ws + 16 * MB);      // 112 MiB [E][2F][H]
    bf16_t* hmid = (bf16_t*)(ws + 128 * MB);     // 126 MiB [MAX_ROWS][F]
    bf16_t* w2t  = (bf16_t*)(ws + 0);            // 56 MiB (after gemm1)
    float*  oasm = (float*)(ws + 56 * MB);       // 72 MiB (after gemm1)
    char* meta = ws + 128 * MB + (size_t)MAX_ROWS * F_DIM * 2;
    int*   asg_tok  = (int*)meta;                meta += MAX_ROWS * 4;
    float* asg_wt   = (float*)meta;              meta += MAX_ROWS * 4;
    int*   tok_slot = (int*)meta;                meta += T_TOK * 2 * 4;
    int*   tok_e    = (int*)meta;                meta += T_TOK * 2 * 4;
    float* tok_w    = (float*)meta;              meta += T_TOK * 2 * 4;
    int*   tm256    = (int*)meta;                meta += MAX_T256 * 2 * 4;
    int*   n256     = (int*)meta;                meta += 4;
    int*   tm128    = (int*)meta;                meta += MAX_T128 * 2 * 4;
    int*   n128     = (int*)meta;                meta += 4;

    const int nx4 = T_TOK * H_DIM / 4;
    const int nw4 = E_NUM * F_DIM * H_DIM / 4;
    cast_f32_to_bf16<<<nx4 / 256, 256, 0, stream>>>(x, xb, nx4);
    cast_interleave_glu<<<nw4 / 256, 256, 0, stream>>>(w1, v1, bcat, nw4);
    router_kernel<<<T_TOK / 4, 256, 0, stream>>>(x, rw, tok_e, tok_w);
    build_assignments<<<1, 1024, 0, stream>>>(tok_e, tok_w, asg_tok, asg_wt, tok_slot,
                                              tm256, n256, tm128, n128);
    gemm1_glu<<<dim3(MAX_T256, NB1), 512, 0, stream>>>(
        xb, bcat, asg_tok, asg_wt, tm256, n256, hmid);
    // xb/bcat dead from here; build w2t over them
    transpose_cast_w2<<<dim3(F_DIM / 32, H_DIM / 32, E_NUM), dim3(32, 8), 0, stream>>>(w2, w2t);
    gemm2_out<<<dim3(MAX_T128, 8), 256, 0, stream>>>(hmid, w2t, tm128, n128, oasm);
    combine_kernel<<<T_TOK, 256, 0, stream>>>(oasm, tok_slot, out);
}